// Round 3
// baseline (383.400 us; speedup 1.0000x reference)
//
#include <hip/hip_runtime.h>

#define N_TOK 262144
#define D_FEAT 128
#define C_CLS 64
#define NBLOCKS 512
#define NTHREADS 512            // 8 waves
#define ROWS_PER_BLOCK 512      // N_TOK / NBLOCKS
// wave owns 64 rows = 4 groups (rt) of 16

typedef __attribute__((ext_vector_type(8))) short bf16x8;
typedef __attribute__((ext_vector_type(4))) float f32x4;

__device__ __forceinline__ unsigned short f2bf(float x) {
    unsigned u = __float_as_uint(x);
    u += 0x7FFFu + ((u >> 16) & 1u);   // RTNE
    return (unsigned short)(u >> 16);
}

__device__ __forceinline__ bf16x8 pack8(f32x4 a, f32x4 b) {
    bf16x8 t;
    t[0] = (short)f2bf(a[0]); t[1] = (short)f2bf(a[1]);
    t[2] = (short)f2bf(a[2]); t[3] = (short)f2bf(a[3]);
    t[4] = (short)f2bf(b[0]); t[5] = (short)f2bf(b[1]);
    t[6] = (short)f2bf(b[2]); t[7] = (short)f2bf(b[3]);
    return t;
}

__device__ __forceinline__ float sq4(f32x4 v) {
    return v[0]*v[0] + v[1]*v[1] + v[2]*v[2] + v[3]*v[3];
}

// Fused: distance GEMM (bf16 MFMA) + per-class segment sums + counts + loss gather.
// f is read exactly once, directly in A-fragment layout. No barriers in main loop.
__global__ __launch_bounds__(NTHREADS, 4) void center_main(
    const float* __restrict__ f, const int* __restrict__ label,
    const float* __restrict__ centers, float* __restrict__ dist_out,
    float* __restrict__ ws_loss, unsigned* __restrict__ ws_cnt,
    float* __restrict__ ws_seg)
{
    __shared__ float    seg[D_FEAT * C_CLS];      // transposed [k][c], 32 KB
    __shared__ short    bfrag[16 * 64 * 8];       // 16 frags x 64 lanes x 8 bf16 = 16 KB
    __shared__ float    c2s[C_CLS];
    __shared__ float    f2w[NTHREADS];            // per local row ||f||^2
    __shared__ int      lblw[NTHREADS];           // per local row label
    __shared__ unsigned cnts[C_CLS];

    const int tid  = threadIdx.x;
    const int lane = tid & 63;
    const int w    = tid >> 6;      // wave 0..7
    const int qk   = lane >> 4;     // k-quad 0..3
    const int ln   = lane & 15;

    // ---- init: zero seg/cnts; wave0 builds B frags + c2; all load labels ----
    for (int i = tid; i < D_FEAT * C_CLS; i += NTHREADS) seg[i] = 0.f;
    if (tid < C_CLS) cnts[tid] = 0u;

    if (w == 0) {
        #pragma unroll
        for (int ct = 0; ct < 4; ++ct) {
            const int n = ln * 4 + ct;            // column this frag produces
            const float* bp = centers + n * D_FEAT + qk * 8;
            float c2p = 0.f;
            #pragma unroll
            for (int ks = 0; ks < 4; ++ks) {
                f32x4 v0 = *(const f32x4*)(bp + ks * 32);
                f32x4 v1 = *(const f32x4*)(bp + ks * 32 + 4);
                c2p += sq4(v0) + sq4(v1);
                *(bf16x8*)(&bfrag[((ct * 4 + ks) * 64 + lane) * 8]) = pack8(v0, v1);
            }
            c2p += __shfl_xor(c2p, 16);
            c2p += __shfl_xor(c2p, 32);
            if (qk == 0) c2s[n] = c2p;
        }
    }

    const int rowbase = blockIdx.x * ROWS_PER_BLOCK;
    const int mylbl   = label[rowbase + tid];     // one row per thread
    lblw[tid] = mylbl;

    __syncthreads();

    atomicAdd(&cnts[mylbl], 1u);                  // after zeroing barrier

    float c2r[4];
    #pragma unroll
    for (int ct = 0; ct < 4; ++ct) c2r[ct] = c2s[ln * 4 + ct];

    float lossa = 0.f;

    for (int rt = 0; rt < 4; ++rt) {
        const int r16 = w * 64 + rt * 16;         // local base row of this 16-row group

        // ---- load A-frag data (f read once, NT) ----
        const float* ap = f + (size_t)(rowbase + r16 + ln) * D_FEAT + qk * 8;
        f32x4 raw[8];
        #pragma unroll
        for (int ks = 0; ks < 4; ++ks) {
            raw[2 * ks]     = __builtin_nontemporal_load((const f32x4*)(ap + ks * 32));
            raw[2 * ks + 1] = __builtin_nontemporal_load((const f32x4*)(ap + ks * 32 + 4));
        }

        // ---- pack to bf16 + fp32 row-norm partial ----
        bf16x8 afr[4];
        float s2 = 0.f;
        #pragma unroll
        for (int ks = 0; ks < 4; ++ks) {
            s2 += sq4(raw[2 * ks]) + sq4(raw[2 * ks + 1]);
            afr[ks] = pack8(raw[2 * ks], raw[2 * ks + 1]);
        }
        s2 += __shfl_xor(s2, 16);
        s2 += __shfl_xor(s2, 32);
        if (qk == 0) f2w[r16 + ln] = s2;

        // ---- segment sums: lane adds its 32 fp32 values of row (r16+ln) ----
        {
            const int lb = lblw[r16 + ln];
            const float* rf = (const float*)raw;
            #pragma unroll
            for (int ks = 0; ks < 4; ++ks)
                #pragma unroll
                for (int j = 0; j < 8; ++j)
                    atomicAdd(&seg[(ks * 32 + qk * 8 + j) * C_CLS + lb], rf[ks * 8 + j]);
        }

        // ---- MFMA: 4 col-groups x 4 k-chunks ----
        f32x4 acc[4];
        #pragma unroll
        for (int ct = 0; ct < 4; ++ct) {
            f32x4 a = {0.f, 0.f, 0.f, 0.f};
            #pragma unroll
            for (int ks = 0; ks < 4; ++ks) {
                bf16x8 bv = *(const bf16x8*)(&bfrag[((ct * 4 + ks) * 64 + lane) * 8]);
                a = __builtin_amdgcn_mfma_f32_16x16x32_bf16(afr[ks], bv, a, 0, 0, 0);
            }
            acc[ct] = a;
        }

        // ---- epilogue: dist rows (coalesced f32x4 NT stores) + loss gather ----
        #pragma unroll
        for (int v = 0; v < 4; ++v) {
            const int rloc = r16 + qk * 4 + v;
            const float fv = f2w[rloc];
            const int  lb2 = lblw[rloc];
            f32x4 o;
            o[0] = fv + c2r[0] - 2.f * acc[0][v];
            o[1] = fv + c2r[1] - 2.f * acc[1][v];
            o[2] = fv + c2r[2] - 2.f * acc[2][v];
            o[3] = fv + c2r[3] - 2.f * acc[3][v];
            const int sub = lb2 & 3;
            const float pick = sub < 2 ? (sub == 0 ? o[0] : o[1])
                                       : (sub == 2 ? o[2] : o[3]);
            if ((lb2 >> 2) == ln) lossa += pick;
            __builtin_nontemporal_store(o,
                (f32x4*)(dist_out + (size_t)(rowbase + rloc) * C_CLS + ln * 4));
        }
    }

    // ---- flush block partials ----
    __syncthreads();
    for (int i = tid; i < D_FEAT * C_CLS; i += NTHREADS)
        unsafeAtomicAdd(&ws_seg[i], seg[i]);
    if (tid < C_CLS) atomicAdd(&ws_cnt[tid], cnts[tid]);
    #pragma unroll
    for (int off = 32; off; off >>= 1) lossa += __shfl_xor(lossa, off);
    if (lane == 0) unsafeAtomicAdd(ws_loss, lossa);
}

__global__ void center_fin(const float* __restrict__ centers,
                           const float* __restrict__ ws_loss,
                           const unsigned* __restrict__ ws_cnt,
                           const float* __restrict__ ws_seg,
                           float* __restrict__ out)
{
    const int i = blockIdx.x * 256 + threadIdx.x;
    if (i == 0) out[0] = ws_loss[0] / ((float)N_TOK * (float)D_FEAT);
    if (i < C_CLS * D_FEAT) {
        const int c = i >> 7;          // class
        const int d = i & 127;         // feature
        const unsigned cnt = ws_cnt[c];
        const float denom = (float)(cnt > 1u ? cnt : 1u);
        out[1 + i] = ((float)cnt * centers[i] - ws_seg[d * C_CLS + c]) / denom;
    }
}

extern "C" void kernel_launch(void* const* d_in, const int* in_sizes, int n_in,
                              void* d_out, int out_size, void* d_ws, size_t ws_size,
                              hipStream_t stream)
{
    const float* f       = (const float*)d_in[0];
    const int*   lbl     = (const int*)d_in[1];
    const float* centers = (const float*)d_in[2];
    float* out = (float*)d_out;

    float*    ws_loss = (float*)d_ws;
    unsigned* ws_cnt  = (unsigned*)((char*)d_ws + 256);
    float*    ws_seg  = (float*)((char*)d_ws + 1024);

    // zero accumulators (ws is poisoned 0xAA before every timed launch)
    (void)hipMemsetAsync(d_ws, 0, 1024 + C_CLS * D_FEAT * sizeof(float), stream);

    float* dist_out = out + 1 + C_CLS * D_FEAT;
    center_main<<<NBLOCKS, NTHREADS, 0, stream>>>(f, lbl, centers, dist_out,
                                                  ws_loss, ws_cnt, ws_seg);
    center_fin<<<32, 256, 0, stream>>>(centers, ws_loss, ws_cnt, ws_seg, out);
}